// Round 1
// baseline (1009.430 us; speedup 1.0000x reference)
//
#include <hip/hip_runtime.h>

// Depthwise temporal FIR, weight-normalized + positive-clamped filters.
// out[t,c] = bias[c] + sum_{f=0..63} max(0, w[f,c]/max(||w[:,c]||,1e-8)) * x[t+f-31, c]
// Layout [T,C] row-major, C fast => thread-per-channel is perfectly coalesced.
// No cross-thread reuse exists (per-channel filters) => register streaming, no LDS.

#define T_DIM 4096
#define C_DIM 4096
#define FWID 64
#define PAD_L 31
#define RPT 32          // outputs (time steps) per thread

template <bool GUARD>
__device__ __forceinline__ void conv_body(const float* __restrict__ x,
                                          const float* __restrict__ w,
                                          const float* __restrict__ b,
                                          float* __restrict__ out,
                                          int c, int t0) {
    // ---- load weights (coalesced across lanes), weight-norm inline ----
    float wf[FWID];
    float ss = 0.0f;
#pragma unroll
    for (int f = 0; f < FWID; ++f) {
        wf[f] = w[f * C_DIM + c];
        ss = fmaf(wf[f], wf[f], ss);
    }
    const float inv = 1.0f / fmaxf(sqrtf(ss), 1e-8f);
#pragma unroll
    for (int f = 0; f < FWID; ++f) wf[f] = fmaxf(wf[f] * inv, 0.0f);

    const float bv = b[c];
    float acc[RPT];
#pragma unroll
    for (int r = 0; r < RPT; ++r) acc[r] = bv;

    // ---- stream R+FW-1 inputs; each feeds up to 64 statically-indexed FMAs ----
    const float* xp = x + (long long)(t0 - PAD_L) * C_DIM + c;
#pragma unroll
    for (int j = 0; j < RPT + FWID - 1; ++j) {
        float xv;
        if (GUARD) {
            const int t = t0 - PAD_L + j;
            xv = (t >= 0 && t < T_DIM) ? xp[(long long)j * C_DIM] : 0.0f;
        } else {
            xv = xp[(long long)j * C_DIM];
        }
        const int rlo = (j - (FWID - 1)) > 0 ? (j - (FWID - 1)) : 0;
        const int rhi = j < (RPT - 1) ? j : (RPT - 1);
#pragma unroll
        for (int r = 0; r < RPT; ++r) {
            if (r >= rlo && r <= rhi)              // folds at compile time (j,r const)
                acc[r] = fmaf(wf[j - r], xv, acc[r]);
        }
    }

    float* op = out + (long long)t0 * C_DIM + c;
#pragma unroll
    for (int r = 0; r < RPT; ++r) op[(long long)r * C_DIM] = acc[r];
}

__global__ __launch_bounds__(256) void depthwise_fir_kernel(
    const float* __restrict__ x, const float* __restrict__ w,
    const float* __restrict__ b, float* __restrict__ out) {
    const int c  = blockIdx.y * 256 + threadIdx.x;
    const int t0 = blockIdx.x * RPT;
    // zero-pad guard needed only at the first/last time tile (block-uniform branch)
    if (blockIdx.x == 0 || blockIdx.x == gridDim.x - 1)
        conv_body<true>(x, w, b, out, c, t0);
    else
        conv_body<false>(x, w, b, out, c, t0);
}

extern "C" void kernel_launch(void* const* d_in, const int* in_sizes, int n_in,
                              void* d_out, int out_size, void* d_ws, size_t ws_size,
                              hipStream_t stream) {
    const float* x = (const float*)d_in[0];   // [T, C]
    const float* w = (const float*)d_in[1];   // [FW, C]
    const float* b = (const float*)d_in[2];   // [C]
    float* out = (float*)d_out;               // [T, C]

    dim3 grid(T_DIM / RPT, C_DIM / 256);      // 128 x 16 blocks
    dim3 block(256);
    hipLaunchKernelGGL(depthwise_fir_kernel, grid, block, 0, stream, x, w, b, out);
}

// Round 2
// 54.227 us; speedup vs baseline: 18.6150x; 18.6150x over previous
//
#include <hip/hip_runtime.h>

// Depthwise temporal FIR (FW=64, SAME pad: low=31, high=32), weight-norm +
// positivity clamp + bias.  out[t,c] = b[c] + sum_f relu(w[f,c]/||w[:,c]||) * x[t-31+f, c]
//
// Round-1 failure: compiler refused the 95-iter forced unroll -> wf[]/acc[]
// runtime-indexed -> scratch (VGPR=40, FETCH=1.38GB, VALUBusy=3.6%).
// Fix: circular register window xbuf[64] with invariant xbuf[m&63]=x[m]
// (t0 % 64 == 0 so every index is a literal), 64 output steps emitted as
// explicit macro expansions, inner 64-tap loop is a small safe unroll.

#define T_DIM 4096
#define C_DIM 4096
#define FWID  64
#define PAD_L 31
#define KTILE 64     // outputs per thread; also the circular-buffer period

template <bool GUARD>
__device__ __forceinline__ void fir_body(const float* __restrict__ x,
                                         const float* __restrict__ w,
                                         const float* __restrict__ b,
                                         float* __restrict__ out,
                                         int c, int t0) {
    const float* __restrict__ xp = x + c;          // column base
    float* __restrict__ op = out + (long long)t0 * C_DIM + c;

    // ---- weight-norm into registers (64 coalesced loads) ----
    float wf[FWID];
    float ss = 0.0f;
#pragma unroll
    for (int f = 0; f < FWID; ++f) {
        wf[f] = w[f * C_DIM + c];
        ss = fmaf(wf[f], wf[f], ss);
    }
    const float inv = 1.0f / fmaxf(sqrtf(ss), 1e-8f);
#pragma unroll
    for (int f = 0; f < FWID; ++f) wf[f] = fmaxf(wf[f] * inv, 0.0f);

    const float bv = b[c];

    // ---- warm-up: xbuf[m & 63] = x[m] for m in [t0-31, t0+32] ----
    float xbuf[KTILE];
#pragma unroll
    for (int i = 0; i < KTILE; ++i) {
        const int m = t0 - PAD_L + i;
        const int s = (i + 33) & 63;               // == m & 63 (t0 % 64 == 0)
        if (!GUARD || ((unsigned)m < (unsigned)T_DIM))
            xbuf[s] = xp[(long long)m * C_DIM];
        else
            xbuf[s] = 0.0f;
    }

    // ---- one output step; k must be a compile-time constant expression ----
#define FIR_STEP(k)                                                          \
    {                                                                        \
        float xn = 0.0f;                                                     \
        if ((k) < KTILE - 1) {                                               \
            const int m = t0 + (k) + 33;                                     \
            if (!GUARD || m < T_DIM) xn = xp[(long long)m * C_DIM];          \
        }                                                                    \
        float a0 = bv, a1 = 0.0f, a2 = 0.0f, a3 = 0.0f;                      \
        _Pragma("unroll")                                                    \
        for (int f = 0; f < FWID; f += 4) {                                  \
            a0 = fmaf(wf[f + 0], xbuf[((k) + f + 33) & 63], a0);             \
            a1 = fmaf(wf[f + 1], xbuf[((k) + f + 34) & 63], a1);             \
            a2 = fmaf(wf[f + 2], xbuf[((k) + f + 35) & 63], a2);             \
            a3 = fmaf(wf[f + 3], xbuf[((k) + f + 36) & 63], a3);             \
        }                                                                    \
        op[(long long)(k) * C_DIM] = (a0 + a1) + (a2 + a3);                  \
        if ((k) < KTILE - 1) xbuf[((k) + 33) & 63] = xn;                     \
    }

#define FIR_STEP8(b) FIR_STEP(b + 0) FIR_STEP(b + 1) FIR_STEP(b + 2)         \
                     FIR_STEP(b + 3) FIR_STEP(b + 4) FIR_STEP(b + 5)         \
                     FIR_STEP(b + 6) FIR_STEP(b + 7)

    FIR_STEP8(0)  FIR_STEP8(8)  FIR_STEP8(16) FIR_STEP8(24)
    FIR_STEP8(32) FIR_STEP8(40) FIR_STEP8(48) FIR_STEP8(56)

#undef FIR_STEP8
#undef FIR_STEP
}

__global__ __launch_bounds__(256) void depthwise_fir_kernel(
    const float* __restrict__ x, const float* __restrict__ w,
    const float* __restrict__ b, float* __restrict__ out) {
    const int c  = blockIdx.y * 256 + threadIdx.x;
    const int t0 = blockIdx.x * KTILE;
    // zero-pad guard only at first/last time tile (block-uniform branch)
    if (blockIdx.x == 0 || blockIdx.x == gridDim.x - 1)
        fir_body<true>(x, w, b, out, c, t0);
    else
        fir_body<false>(x, w, b, out, c, t0);
}

extern "C" void kernel_launch(void* const* d_in, const int* in_sizes, int n_in,
                              void* d_out, int out_size, void* d_ws, size_t ws_size,
                              hipStream_t stream) {
    const float* x = (const float*)d_in[0];   // [T, C]
    const float* w = (const float*)d_in[1];   // [FW, C]
    const float* b = (const float*)d_in[2];   // [C]
    float* out = (float*)d_out;               // [T, C]

    dim3 grid(T_DIM / KTILE, C_DIM / 256);    // 64 x 16 blocks
    dim3 block(256);
    hipLaunchKernelGGL(depthwise_fir_kernel, grid, block, 0, stream, x, w, b, out);
}

// Round 3
// 49.652 us; speedup vs baseline: 20.3299x; 1.0921x over previous
//
#include <hip/hip_runtime.h>

// Depthwise temporal FIR (FW=64, SAME pad low=31/high=32), weight-norm +
// positivity clamp + bias. Thread-per-channel register streaming, circular
// window xbuf[64] (t0 % 64 == 0 so all slot indices are literals).
//
// Round-2 result: 54 us, VALUBusy 50%, HBM 29% -> latency-bound. Load->use
// distance was ~1 step. Round-3 fix: double-buffered 8-deep batch prefetch
// (issue group g+1's loads before group g's FMAs) -> distance ~8 steps
// (~1024 own-issue cycles > ~900 cy HBM latency). Nontemporal C-writes.

#define T_DIM 4096
#define C_DIM 4096
#define FWID  64
#define PAD_L 31
#define KTILE 64     // outputs per thread; also the circular-buffer period
#define GRP   8      // prefetch batch depth

template <bool GUARD>
__device__ __forceinline__ void fir_body(const float* __restrict__ x,
                                         const float* __restrict__ w,
                                         const float* __restrict__ b,
                                         float* __restrict__ out,
                                         int c, int t0) {
    const float* __restrict__ xp = x + c;          // column base
    float* __restrict__ op = out + (long long)t0 * C_DIM + c;

    // ---- weight-norm into registers (64 coalesced loads) ----
    float wf[FWID];
    float ss = 0.0f;
#pragma unroll
    for (int f = 0; f < FWID; ++f) {
        wf[f] = w[f * C_DIM + c];
        ss = fmaf(wf[f], wf[f], ss);
    }
    const float inv = 1.0f / fmaxf(sqrtf(ss), 1e-8f);
#pragma unroll
    for (int f = 0; f < FWID; ++f) wf[f] = fmaxf(wf[f] * inv, 0.0f);

    const float bv = b[c];

    // ---- warm-up: xbuf[m & 63] = x[m] for m in [t0-31, t0+32] ----
    float xbuf[KTILE];
#pragma unroll
    for (int i = 0; i < KTILE; ++i) {
        const int m = t0 - PAD_L + i;
        const int s = (i + 33) & 63;               // == m & 63 (t0 % 64 == 0)
        if (!GUARD || ((unsigned)m < (unsigned)T_DIM))
            xbuf[s] = xp[(long long)m * C_DIM];
        else
            xbuf[s] = 0.0f;
    }

    float xnA[GRP], xnB[GRP];

    // batch-load the 8 x values consumed by group g's steps (k = g*8 .. g*8+7)
#define PREFETCH(dst, g)                                                      \
    _Pragma("unroll")                                                         \
    for (int i = 0; i < GRP; ++i) {                                           \
        const int k = (g) * GRP + i;                                          \
        const int m = t0 + k + 33;                                            \
        float v = 0.0f;                                                       \
        if (k < KTILE - 1 && (!GUARD || m < T_DIM))                           \
            v = xp[(long long)m * C_DIM];                                     \
        dst[i] = v;                                                           \
    }

    // one output step; k must be a compile-time constant expression
#define FIR_STEP(k, src)                                                      \
    {                                                                         \
        float a0 = bv, a1 = 0.0f, a2 = 0.0f, a3 = 0.0f;                       \
        _Pragma("unroll")                                                     \
        for (int f = 0; f < FWID; f += 4) {                                   \
            a0 = fmaf(wf[f + 0], xbuf[((k) + f + 33) & 63], a0);              \
            a1 = fmaf(wf[f + 1], xbuf[((k) + f + 34) & 63], a1);              \
            a2 = fmaf(wf[f + 2], xbuf[((k) + f + 35) & 63], a2);              \
            a3 = fmaf(wf[f + 3], xbuf[((k) + f + 36) & 63], a3);              \
        }                                                                     \
        __builtin_nontemporal_store((a0 + a1) + (a2 + a3),                    \
                                    op + (long long)(k) * C_DIM);             \
        if ((k) < KTILE - 1) xbuf[((k) + 33) & 63] = src[(k) & 7];            \
    }

#define GROUP(g, src)                                                         \
    FIR_STEP((g) * 8 + 0, src) FIR_STEP((g) * 8 + 1, src)                     \
    FIR_STEP((g) * 8 + 2, src) FIR_STEP((g) * 8 + 3, src)                     \
    FIR_STEP((g) * 8 + 4, src) FIR_STEP((g) * 8 + 5, src)                     \
    FIR_STEP((g) * 8 + 6, src) FIR_STEP((g) * 8 + 7, src)

    // software pipeline: prefetch group g+1 before computing group g
    PREFETCH(xnA, 0)
    PREFETCH(xnB, 1) GROUP(0, xnA)
    PREFETCH(xnA, 2) GROUP(1, xnB)
    PREFETCH(xnB, 3) GROUP(2, xnA)
    PREFETCH(xnA, 4) GROUP(3, xnB)
    PREFETCH(xnB, 5) GROUP(4, xnA)
    PREFETCH(xnA, 6) GROUP(5, xnB)
    PREFETCH(xnB, 7) GROUP(6, xnA)
    GROUP(7, xnB)

#undef GROUP
#undef FIR_STEP
#undef PREFETCH
}

__global__ __launch_bounds__(256) void depthwise_fir_kernel(
    const float* __restrict__ x, const float* __restrict__ w,
    const float* __restrict__ b, float* __restrict__ out) {
    const int c  = blockIdx.y * 256 + threadIdx.x;
    const int t0 = blockIdx.x * KTILE;
    // zero-pad guard only at first/last time tile (block-uniform branch)
    if (blockIdx.x == 0 || blockIdx.x == gridDim.x - 1)
        fir_body<true>(x, w, b, out, c, t0);
    else
        fir_body<false>(x, w, b, out, c, t0);
}

extern "C" void kernel_launch(void* const* d_in, const int* in_sizes, int n_in,
                              void* d_out, int out_size, void* d_ws, size_t ws_size,
                              hipStream_t stream) {
    const float* x = (const float*)d_in[0];   // [T, C]
    const float* w = (const float*)d_in[1];   // [FW, C]
    const float* b = (const float*)d_in[2];   // [C]
    float* out = (float*)d_out;               // [T, C]

    dim3 grid(T_DIM / KTILE, C_DIM / 256);    // 64 x 16 blocks
    dim3 block(256);
    hipLaunchKernelGGL(depthwise_fir_kernel, grid, block, 0, stream, x, w, b, out);
}

// Round 4
// 47.841 us; speedup vs baseline: 21.0998x; 1.0379x over previous
//
#include <hip/hip_runtime.h>

// Depthwise temporal FIR (FW=64, SAME pad low=31/high=32), weight-norm +
// positivity clamp + bias. Thread-per-channel register streaming, circular
// window xbuf[64] (t0 % 64 == 0 so all slot indices are literals).
//
// Round-2 result: 54 us, VALUBusy 50%, HBM 29% -> latency-bound. Load->use
// distance was ~1 step. Round-3 fix: double-buffered 8-deep batch prefetch
// (issue group g+1's loads before group g's FMAs) -> distance ~8 steps
// (~1024 own-issue cycles > ~900 cy HBM latency). Nontemporal C-writes.

#define T_DIM 4096
#define C_DIM 4096
#define FWID  64
#define PAD_L 31
#define KTILE 64     // outputs per thread; also the circular-buffer period
#define GRP   8      // prefetch batch depth

template <bool GUARD>
__device__ __forceinline__ void fir_body(const float* __restrict__ x,
                                         const float* __restrict__ w,
                                         const float* __restrict__ b,
                                         float* __restrict__ out,
                                         int c, int t0) {
    const float* __restrict__ xp = x + c;          // column base
    float* __restrict__ op = out + (long long)t0 * C_DIM + c;

    // ---- weight-norm into registers (64 coalesced loads) ----
    float wf[FWID];
    float ss = 0.0f;
#pragma unroll
    for (int f = 0; f < FWID; ++f) {
        wf[f] = w[f * C_DIM + c];
        ss = fmaf(wf[f], wf[f], ss);
    }
    const float inv = 1.0f / fmaxf(sqrtf(ss), 1e-8f);
#pragma unroll
    for (int f = 0; f < FWID; ++f) wf[f] = fmaxf(wf[f] * inv, 0.0f);

    const float bv = b[c];

    // ---- warm-up: xbuf[m & 63] = x[m] for m in [t0-31, t0+32] ----
    float xbuf[KTILE];
#pragma unroll
    for (int i = 0; i < KTILE; ++i) {
        const int m = t0 - PAD_L + i;
        const int s = (i + 33) & 63;               // == m & 63 (t0 % 64 == 0)
        if (!GUARD || ((unsigned)m < (unsigned)T_DIM))
            xbuf[s] = xp[(long long)m * C_DIM];
        else
            xbuf[s] = 0.0f;
    }

    float xnA[GRP], xnB[GRP];

    // batch-load the 8 x values consumed by group g's steps (k = g*8 .. g*8+7)
#define PREFETCH(dst, g)                                                      \
    _Pragma("unroll")                                                         \
    for (int i = 0; i < GRP; ++i) {                                           \
        const int k = (g) * GRP + i;                                          \
        const int m = t0 + k + 33;                                            \
        float v = 0.0f;                                                       \
        if (k < KTILE - 1 && (!GUARD || m < T_DIM))                           \
            v = xp[(long long)m * C_DIM];                                     \
        dst[i] = v;                                                           \
    }

    // one output step; k must be a compile-time constant expression
#define FIR_STEP(k, src)                                                      \
    {                                                                         \
        float a0 = bv, a1 = 0.0f, a2 = 0.0f, a3 = 0.0f;                       \
        _Pragma("unroll")                                                     \
        for (int f = 0; f < FWID; f += 4) {                                   \
            a0 = fmaf(wf[f + 0], xbuf[((k) + f + 33) & 63], a0);              \
            a1 = fmaf(wf[f + 1], xbuf[((k) + f + 34) & 63], a1);              \
            a2 = fmaf(wf[f + 2], xbuf[((k) + f + 35) & 63], a2);              \
            a3 = fmaf(wf[f + 3], xbuf[((k) + f + 36) & 63], a3);              \
        }                                                                     \
        __builtin_nontemporal_store((a0 + a1) + (a2 + a3),                    \
                                    op + (long long)(k) * C_DIM);             \
        if ((k) < KTILE - 1) xbuf[((k) + 33) & 63] = src[(k) & 7];            \
    }

#define GROUP(g, src)                                                         \
    FIR_STEP((g) * 8 + 0, src) FIR_STEP((g) * 8 + 1, src)                     \
    FIR_STEP((g) * 8 + 2, src) FIR_STEP((g) * 8 + 3, src)                     \
    FIR_STEP((g) * 8 + 4, src) FIR_STEP((g) * 8 + 5, src)                     \
    FIR_STEP((g) * 8 + 6, src) FIR_STEP((g) * 8 + 7, src)

    // software pipeline: prefetch group g+1 before computing group g
    PREFETCH(xnA, 0)
    PREFETCH(xnB, 1) GROUP(0, xnA)
    PREFETCH(xnA, 2) GROUP(1, xnB)
    PREFETCH(xnB, 3) GROUP(2, xnA)
    PREFETCH(xnA, 4) GROUP(3, xnB)
    PREFETCH(xnB, 5) GROUP(4, xnA)
    PREFETCH(xnA, 6) GROUP(5, xnB)
    PREFETCH(xnB, 7) GROUP(6, xnA)
    GROUP(7, xnB)

#undef GROUP
#undef FIR_STEP
#undef PREFETCH
}

__global__ __launch_bounds__(256) void depthwise_fir_kernel(
    const float* __restrict__ x, const float* __restrict__ w,
    const float* __restrict__ b, float* __restrict__ out) {
    const int c  = blockIdx.y * 256 + threadIdx.x;
    const int t0 = blockIdx.x * KTILE;
    // zero-pad guard only at first/last time tile (block-uniform branch)
    if (blockIdx.x == 0 || blockIdx.x == gridDim.x - 1)
        fir_body<true>(x, w, b, out, c, t0);
    else
        fir_body<false>(x, w, b, out, c, t0);
}

extern "C" void kernel_launch(void* const* d_in, const int* in_sizes, int n_in,
                              void* d_out, int out_size, void* d_ws, size_t ws_size,
                              hipStream_t stream) {
    const float* x = (const float*)d_in[0];   // [T, C]
    const float* w = (const float*)d_in[1];   // [FW, C]
    const float* b = (const float*)d_in[2];   // [C]
    float* out = (float*)d_out;               // [T, C]

    dim3 grid(T_DIM / KTILE, C_DIM / 256);    // 64 x 16 blocks
    dim3 block(256);
    hipLaunchKernelGGL(depthwise_fir_kernel, grid, block, 0, stream, x, w, b, out);
}